// Round 1
// baseline (1092.207 us; speedup 1.0000x reference)
//
#include <hip/hip_runtime.h>

// CTAttention: octree dilated window attention, MI355X gfx950.
// Pipeline: f32->bf16 convert -> QKV GEMM (MFMA bf16) -> windowed attention -> proj GEMM.
// Dilation reshuffle is a row permutation p(w,k) = (w/4)*96 + k*4 + (w%4), applied
// only inside the attention kernel; GEMMs run in original token order.

#define N_TOK 500000
#define NA    500064          // ceil(N/96)*96
#define MP    500096          // NA rounded up to 128-row GEMM tiles
#define CDIM  256
#define KWIN  24
#define NWIN  20836           // NA / 24
#define HEADS 8
#define HDIM  32
#define SCALE_F 0.17677669529663689f
#define MASKV  -1000.0f

typedef __attribute__((ext_vector_type(8))) short bf16x8;
typedef __attribute__((ext_vector_type(4))) float f32x4;

__device__ __forceinline__ unsigned short f2b(float f) {
    unsigned int u = __float_as_uint(f);
    u += 0x7fffu + ((u >> 16) & 1u);        // round-to-nearest-even
    return (unsigned short)(u >> 16);
}
__device__ __forceinline__ float b2f_lo(unsigned int x) { return __uint_as_float(x << 16); }
__device__ __forceinline__ float b2f_hi(unsigned int x) { return __uint_as_float(x & 0xffff0000u); }

#define GLOAD_LDS16(gsrc, ldst) \
    __builtin_amdgcn_global_load_lds((const __attribute__((address_space(1))) void*)(gsrc), \
                                     (__attribute__((address_space(3))) void*)(ldst), 16, 0, 0)

// ---------------- conversion kernels ----------------

__global__ __launch_bounds__(256) void cvt_data_kernel(const float* __restrict__ src,
                                                       unsigned short* __restrict__ dst) {
    long long i = (long long)blockIdx.x * 256 + threadIdx.x;   // one 8-elem chunk
    long long base = i * 8;
    int row = (int)(base >> 8);
    uint4 o;
    if (row < N_TOK) {
        float4 a = *(const float4*)(src + base);
        float4 b = *(const float4*)(src + base + 4);
        o.x = (unsigned)f2b(a.x) | ((unsigned)f2b(a.y) << 16);
        o.y = (unsigned)f2b(a.z) | ((unsigned)f2b(a.w) << 16);
        o.z = (unsigned)f2b(b.x) | ((unsigned)f2b(b.y) << 16);
        o.w = (unsigned)f2b(b.z) | ((unsigned)f2b(b.w) << 16);
    } else {
        o = make_uint4(0u, 0u, 0u, 0u);   // zero pad rows [N_TOK, MP)
    }
    *(uint4*)(dst + base) = o;
}

__global__ __launch_bounds__(256) void cvt_w_kernel(const float* __restrict__ src,
                                                    unsigned short* __restrict__ dst, int n8) {
    int i = blockIdx.x * 256 + threadIdx.x;
    if (i >= n8) return;
    float4 a = ((const float4*)src)[i * 2];
    float4 b = ((const float4*)src)[i * 2 + 1];
    uint4 o;
    o.x = (unsigned)f2b(a.x) | ((unsigned)f2b(a.y) << 16);
    o.y = (unsigned)f2b(a.z) | ((unsigned)f2b(a.w) << 16);
    o.z = (unsigned)f2b(b.x) | ((unsigned)f2b(b.y) << 16);
    o.w = (unsigned)f2b(b.z) | ((unsigned)f2b(b.w) << 16);
    ((uint4*)dst)[i] = o;
}

__global__ __launch_bounds__(256) void zero_pad_kernel(unsigned short* __restrict__ dst) {
    // zero attnB rows [N_TOK, MP)
    int i = blockIdx.x * 256 + threadIdx.x;
    if (i < (MP - N_TOK) * CDIM / 8)
        *(uint4*)(dst + (size_t)N_TOK * CDIM + (size_t)i * 8) = make_uint4(0u, 0u, 0u, 0u);
}

// ---------------- GEMM: out[M][NN] = A[M][256] * Bt[NN][256]^T + bias ----------------
// 128x128 tile, BK=64, 4 waves (2x2 of 64x64), mfma_f32_16x16x32_bf16.

template<int NN, bool OUT_F32>
__global__ __launch_bounds__(256, 2) void gemm_kernel(const unsigned short* __restrict__ A,
                                                      const unsigned short* __restrict__ Bt,
                                                      const float* __restrict__ bias,
                                                      void* __restrict__ out_p,
                                                      int m_write) {
    __shared__ unsigned short ldsA[128 * 64];
    __shared__ unsigned short ldsB[128 * 64];
    const int tid  = threadIdx.x;
    const int lane = tid & 63;
    const int wv   = tid >> 6;
    const int wr   = wv >> 1, wc = wv & 1;
    const int mtile = blockIdx.y, ntile = blockIdx.x;

    f32x4 acc[4][4];
    #pragma unroll
    for (int i = 0; i < 4; ++i) {
        #pragma unroll
        for (int j = 0; j < 4; ++j) {
            #pragma unroll
            for (int r = 0; r < 4; ++r) acc[i][j][r] = 0.f;
        }
    }

    const char* abase = (const char*)(A  + (size_t)mtile * 128 * CDIM);
    const char* bbase = (const char*)(Bt + (size_t)ntile * 128 * CDIM);
    const int lrow8 = lane >> 3;
    const int lcolb = (lane & 7) * 16;

    for (int kt = 0; kt < 4; ++kt) {
        const int kb_byte = kt * 128;          // kt*64 bf16
        #pragma unroll
        for (int c = 0; c < 4; ++c) {
            int chunk = wv * 4 + c;
            int row = chunk * 8 + lrow8;
            GLOAD_LDS16(abase + (size_t)row * 512 + kb_byte + lcolb, &ldsA[chunk * 512]);
        }
        #pragma unroll
        for (int c = 0; c < 4; ++c) {
            int chunk = wv * 4 + c;
            int row = chunk * 8 + lrow8;
            GLOAD_LDS16(bbase + (size_t)row * 512 + kb_byte + lcolb, &ldsB[chunk * 512]);
        }
        __syncthreads();                        // drains vmcnt + barrier
        #pragma unroll
        for (int ks = 0; ks < 2; ++ks) {
            const int kb = ks * 32 + (lane >> 4) * 8;
            bf16x8 af[4], bfr[4];
            #pragma unroll
            for (int i = 0; i < 4; ++i) {
                af[i]  = *(const bf16x8*)&ldsA[(wr * 64 + i * 16 + (lane & 15)) * 64 + kb];
                bfr[i] = *(const bf16x8*)&ldsB[(wc * 64 + i * 16 + (lane & 15)) * 64 + kb];
            }
            #pragma unroll
            for (int i = 0; i < 4; ++i) {
                #pragma unroll
                for (int j = 0; j < 4; ++j)
                    acc[i][j] = __builtin_amdgcn_mfma_f32_16x16x32_bf16(af[i], bfr[j], acc[i][j], 0, 0, 0);
            }
        }
        __syncthreads();
    }

    // epilogue: C/D layout col=lane&15, row=(lane>>4)*4+reg
    #pragma unroll
    for (int i = 0; i < 4; ++i) {
        int row0 = mtile * 128 + wr * 64 + i * 16 + ((lane >> 4) << 2);
        #pragma unroll
        for (int j = 0; j < 4; ++j) {
            int col = ntile * 128 + wc * 64 + j * 16 + (lane & 15);
            float bv = bias[col];
            #pragma unroll
            for (int r = 0; r < 4; ++r) {
                int row = row0 + r;
                float v = acc[i][j][r] + bv;
                if (OUT_F32) {
                    if (row < m_write) ((float*)out_p)[(size_t)row * NN + col] = v;
                } else {
                    ((unsigned short*)out_p)[(size_t)row * NN + col] = f2b(v);
                }
            }
        }
    }
}

// ---------------- windowed attention ----------------
// One block per window (24 tokens, all 8 heads). qkv window rows staged to LDS
// via global_load_lds; thread (h, q) computes one softmax row in f32.

__global__ __launch_bounds__(256) void attn_kernel(const unsigned short* __restrict__ qkv,
                                                   const int* __restrict__ batch_idx,
                                                   unsigned short* __restrict__ attn_out) {
    __shared__ unsigned short sq[KWIN * 768];   // 36,864 B: [k][c], c: q|k|v interleaved 3*256
    __shared__ int sbi[KWIN];
    const int w = blockIdx.x;
    const int g = w >> 2, dd = w & 3;
    const int tid = threadIdx.x;
    const int wv = tid >> 6;

    // stage 24 rows x 1536 B = 2304 x 16B chunks
    #pragma unroll
    for (int c = 0; c < 9; ++c) {
        int chunk = c * 256 + tid;
        int row = chunk / 96;
        int within = chunk - row * 96;
        int p = g * 96 + row * 4 + dd;
        const char* src = (const char*)qkv + (size_t)p * 1536 + within * 16;
        GLOAD_LDS16(src, &sq[(c * 256 + wv * 64) * 8]);
    }
    if (tid < KWIN) {
        int p = g * 96 + tid * 4 + dd;
        sbi[tid] = (p < N_TOK) ? batch_idx[p] : 8;   // pad batch = BATCH_SIZE
    }
    __syncthreads();

    const int h = tid / 24;
    const int q = tid - h * 24;
    if (h < HEADS) {
        float Q[32];
        const unsigned int* qp = (const unsigned int*)&sq[q * 768 + h * 32];
        #pragma unroll
        for (int c = 0; c < 16; ++c) {
            unsigned int x = qp[c];
            Q[c * 2]     = b2f_lo(x);
            Q[c * 2 + 1] = b2f_hi(x);
        }
        const int bq = sbi[q];
        float s[KWIN];
        float mx = -3.0e38f;
        for (int k = 0; k < KWIN; ++k) {
            const unsigned int* kp = (const unsigned int*)&sq[k * 768 + 256 + h * 32];
            float dot = 0.f;
            #pragma unroll
            for (int c = 0; c < 16; ++c) {
                unsigned int x = kp[c];
                dot += Q[c * 2] * b2f_lo(x) + Q[c * 2 + 1] * b2f_hi(x);
            }
            float v = dot * SCALE_F + ((sbi[k] == bq) ? 0.f : MASKV);
            s[k] = v;
            mx = fmaxf(mx, v);
        }
        float sum = 0.f;
        for (int k = 0; k < KWIN; ++k) { float e = __expf(s[k] - mx); s[k] = e; sum += e; }
        const float inv = 1.f / sum;
        float O[32];
        #pragma unroll
        for (int c = 0; c < 32; ++c) O[c] = 0.f;
        for (int k = 0; k < KWIN; ++k) {
            float pw = s[k] * inv;
            const unsigned int* vp = (const unsigned int*)&sq[k * 768 + 512 + h * 32];
            #pragma unroll
            for (int c = 0; c < 16; ++c) {
                unsigned int x = vp[c];
                O[c * 2]     += pw * b2f_lo(x);
                O[c * 2 + 1] += pw * b2f_hi(x);
            }
        }
        int p = g * 96 + q * 4 + dd;
        if (p < N_TOK) {
            uint4* op = (uint4*)(attn_out + (size_t)p * CDIM + h * HDIM);
            #pragma unroll
            for (int c = 0; c < 4; ++c) {
                uint4 o;
                o.x = (unsigned)f2b(O[c * 8 + 0]) | ((unsigned)f2b(O[c * 8 + 1]) << 16);
                o.y = (unsigned)f2b(O[c * 8 + 2]) | ((unsigned)f2b(O[c * 8 + 3]) << 16);
                o.z = (unsigned)f2b(O[c * 8 + 4]) | ((unsigned)f2b(O[c * 8 + 5]) << 16);
                o.w = (unsigned)f2b(O[c * 8 + 6]) | ((unsigned)f2b(O[c * 8 + 7]) << 16);
                op[c] = o;
            }
        }
    }
}

// ---------------- host launch ----------------

extern "C" void kernel_launch(void* const* d_in, const int* in_sizes, int n_in,
                              void* d_out, int out_size, void* d_ws, size_t ws_size,
                              hipStream_t stream) {
    const float* data    = (const float*)d_in[0];
    const float* qkv_w   = (const float*)d_in[1];
    const float* qkv_b   = (const float*)d_in[2];
    const float* proj_w  = (const float*)d_in[3];
    const float* proj_b  = (const float*)d_in[4];
    const int*   batch_i = (const int*)d_in[5];

    char* ws = (char*)d_ws;
    size_t off = 0;
    unsigned short* dataB  = (unsigned short*)(ws + off); off += (size_t)MP * CDIM * 2;  // 256 MB
    unsigned short* qkvB   = (unsigned short*)(ws + off); off += (size_t)MP * 768 * 2;   // 768 MB
    unsigned short* attnB  = (unsigned short*)(ws + off); off += (size_t)MP * CDIM * 2;  // 256 MB
    unsigned short* wqkvB  = (unsigned short*)(ws + off); off += (size_t)768 * 256 * 2;
    unsigned short* wprojB = (unsigned short*)(ws + off); off += (size_t)256 * 256 * 2;
    if (ws_size < off) return;   // insufficient scratch — cannot compute

    cvt_data_kernel<<<MP / 8, 256, 0, stream>>>(data, dataB);
    cvt_w_kernel<<<(768 * 256 / 8 + 255) / 256, 256, 0, stream>>>(qkv_w, wqkvB, 768 * 256 / 8);
    cvt_w_kernel<<<(256 * 256 / 8 + 255) / 256, 256, 0, stream>>>(proj_w, wprojB, 256 * 256 / 8);
    zero_pad_kernel<<<12, 256, 0, stream>>>(attnB);

    gemm_kernel<768, false><<<dim3(6, MP / 128), 256, 0, stream>>>(dataB, wqkvB, qkv_b, qkvB, MP);
    attn_kernel<<<NWIN, 256, 0, stream>>>(qkvB, batch_i, attnB);
    gemm_kernel<256, true><<<dim3(2, MP / 128), 256, 0, stream>>>(attnB, wprojB, proj_b, d_out, N_TOK);
}

// Round 3
// 1007.313 us; speedup vs baseline: 1.0843x; 1.0843x over previous
//
#include <hip/hip_runtime.h>

// CTAttention: octree dilated window attention, MI355X gfx950.
// f32->bf16 convert -> QKV GEMM (MFMA bf16) -> windowed MFMA attention -> proj GEMM.
// Dilation reshuffle is the row permutation p(w,k) = (w/4)*96 + k*4 + (w%4).

#define N_TOK 500000
#define NA    500064          // ceil(N/96)*96
#define MP    500096          // NA rounded up to 128-row GEMM tiles
#define CDIM  256
#define KWIN  24
#define NWIN  20836           // NA / 24
#define HEADS 8
#define SCALE_F 0.17677669529663689f

typedef __attribute__((ext_vector_type(8))) short bf16x8;
typedef __attribute__((ext_vector_type(4))) float f32x4;

__device__ __forceinline__ unsigned short f2b(float f) {
    unsigned int u = __float_as_uint(f);
    u += 0x7fffu + ((u >> 16) & 1u);        // round-to-nearest-even
    return (unsigned short)(u >> 16);
}

#define GLOAD_LDS16(gsrc, ldst) \
    __builtin_amdgcn_global_load_lds((const __attribute__((address_space(1))) void*)(gsrc), \
                                     (__attribute__((address_space(3))) void*)(ldst), 16, 0, 0)

// ---------------- conversion kernels ----------------

__global__ __launch_bounds__(256) void cvt_data_kernel(const float* __restrict__ src,
                                                       unsigned short* __restrict__ dst) {
    long long i = (long long)blockIdx.x * 256 + threadIdx.x;   // one 8-elem chunk
    long long base = i * 8;
    int row = (int)(base >> 8);
    uint4 o;
    if (row < N_TOK) {
        float4 a = *(const float4*)(src + base);
        float4 b = *(const float4*)(src + base + 4);
        o.x = (unsigned)f2b(a.x) | ((unsigned)f2b(a.y) << 16);
        o.y = (unsigned)f2b(a.z) | ((unsigned)f2b(a.w) << 16);
        o.z = (unsigned)f2b(b.x) | ((unsigned)f2b(b.y) << 16);
        o.w = (unsigned)f2b(b.z) | ((unsigned)f2b(b.w) << 16);
    } else {
        o = make_uint4(0u, 0u, 0u, 0u);   // zero pad rows [N_TOK, MP)
    }
    *(uint4*)(dst + base) = o;
}

__global__ __launch_bounds__(256) void cvt_w_kernel(const float* __restrict__ src,
                                                    unsigned short* __restrict__ dst, int n8) {
    int i = blockIdx.x * 256 + threadIdx.x;
    if (i >= n8) return;
    float4 a = ((const float4*)src)[i * 2];
    float4 b = ((const float4*)src)[i * 2 + 1];
    uint4 o;
    o.x = (unsigned)f2b(a.x) | ((unsigned)f2b(a.y) << 16);
    o.y = (unsigned)f2b(a.z) | ((unsigned)f2b(a.w) << 16);
    o.z = (unsigned)f2b(b.x) | ((unsigned)f2b(b.y) << 16);
    o.w = (unsigned)f2b(b.z) | ((unsigned)f2b(b.w) << 16);
    ((uint4*)dst)[i] = o;
}

__global__ __launch_bounds__(256) void zero_pad_kernel(unsigned short* __restrict__ dst) {
    // zero attnB rows [N_TOK, MP)
    int i = blockIdx.x * 256 + threadIdx.x;
    if (i < (MP - N_TOK) * CDIM / 8)
        *(uint4*)(dst + (size_t)N_TOK * CDIM + (size_t)i * 8) = make_uint4(0u, 0u, 0u, 0u);
}

// ---------------- GEMM: out[M][NN] = A[M][256] * Bt[NN][256]^T + bias ----------------
// 128x128 tile, BK=64, 4 waves (2x2 of 64x64), mfma_f32_16x16x32_bf16.

template<int NN, bool OUT_F32>
__global__ __launch_bounds__(256, 2) void gemm_kernel(const unsigned short* __restrict__ A,
                                                      const unsigned short* __restrict__ Bt,
                                                      const float* __restrict__ bias,
                                                      void* __restrict__ out_p,
                                                      int m_write) {
    __shared__ unsigned short ldsA[128 * 64];
    __shared__ unsigned short ldsB[128 * 64];
    const int tid  = threadIdx.x;
    const int lane = tid & 63;
    const int wv   = tid >> 6;
    const int wr   = wv >> 1, wc = wv & 1;
    const int mtile = blockIdx.y, ntile = blockIdx.x;

    f32x4 acc[4][4];
    #pragma unroll
    for (int i = 0; i < 4; ++i) {
        #pragma unroll
        for (int j = 0; j < 4; ++j) {
            #pragma unroll
            for (int r = 0; r < 4; ++r) acc[i][j][r] = 0.f;
        }
    }

    const char* abase = (const char*)(A  + (size_t)mtile * 128 * CDIM);
    const char* bbase = (const char*)(Bt + (size_t)ntile * 128 * CDIM);
    const int lrow8 = lane >> 3;
    const int lcolb = (lane & 7) * 16;

    for (int kt = 0; kt < 4; ++kt) {
        const int kb_byte = kt * 128;          // kt*64 bf16
        #pragma unroll
        for (int c = 0; c < 4; ++c) {
            int chunk = wv * 4 + c;
            int row = chunk * 8 + lrow8;
            GLOAD_LDS16(abase + (size_t)row * 512 + kb_byte + lcolb, &ldsA[chunk * 512]);
        }
        #pragma unroll
        for (int c = 0; c < 4; ++c) {
            int chunk = wv * 4 + c;
            int row = chunk * 8 + lrow8;
            GLOAD_LDS16(bbase + (size_t)row * 512 + kb_byte + lcolb, &ldsB[chunk * 512]);
        }
        __syncthreads();                        // drains vmcnt + barrier
        #pragma unroll
        for (int ks = 0; ks < 2; ++ks) {
            const int kb = ks * 32 + (lane >> 4) * 8;
            bf16x8 af[4], bfr[4];
            #pragma unroll
            for (int i = 0; i < 4; ++i) {
                af[i]  = *(const bf16x8*)&ldsA[(wr * 64 + i * 16 + (lane & 15)) * 64 + kb];
                bfr[i] = *(const bf16x8*)&ldsB[(wc * 64 + i * 16 + (lane & 15)) * 64 + kb];
            }
            #pragma unroll
            for (int i = 0; i < 4; ++i) {
                #pragma unroll
                for (int j = 0; j < 4; ++j)
                    acc[i][j] = __builtin_amdgcn_mfma_f32_16x16x32_bf16(af[i], bfr[j], acc[i][j], 0, 0, 0);
            }
        }
        __syncthreads();
    }

    // epilogue: C/D layout col=lane&15, row=(lane>>4)*4+reg
    #pragma unroll
    for (int i = 0; i < 4; ++i) {
        int row0 = mtile * 128 + wr * 64 + i * 16 + ((lane >> 4) << 2);
        #pragma unroll
        for (int j = 0; j < 4; ++j) {
            int col = ntile * 128 + wc * 64 + j * 16 + (lane & 15);
            float bv = bias[col];
            #pragma unroll
            for (int r = 0; r < 4; ++r) {
                int row = row0 + r;
                float v = acc[i][j][r] + bv;
                if (OUT_F32) {
                    if (row < m_write) ((float*)out_p)[(size_t)row * NN + col] = v;
                } else {
                    ((unsigned short*)out_p)[(size_t)row * NN + col] = f2b(v);
                }
            }
        }
    }
}

// ---------------- windowed MFMA attention, one wave = one (window, head) ----------------
// No staging, no barriers. Q/K: coalesced bf16x8 global loads. V: 16 scalar u16
// global loads (k-transposed gather, one 64B line per k-row per wave).
// P transposes through a wave-private swizzled LDS buffer (plain C indexing).

__global__ __launch_bounds__(256) void attn_kernel(const unsigned short* __restrict__ qkv,
                                                   const int* __restrict__ batch_idx,
                                                   unsigned short* __restrict__ attn_out) {
    __shared__ unsigned short sP[4][32 * 64];       // per-wave 32x32 P, row stride 64 elems (128B)
    const int tid  = threadIdx.x;
    const int lane = tid & 63;
    const int ws_  = tid >> 6;
    const int wid  = blockIdx.x * 4 + ws_;          // (window, head) task
    const int w = wid >> 3, h = wid & 7;
    const int gw = w >> 2, dd = w & 3;
    const int lrow = lane & 15, lg = lane >> 4;
    const int pbase = gw * 96 + dd;                 // token row = pbase + r*4, r in [0,32)

    // ---- Q, K fragments: A/B layout row|n = lane&15, k = lg*8 + 0..7 ----
    bf16x8 Qf[2], Kf[2];
    #pragma unroll
    for (int t = 0; t < 2; ++t) {
        size_t p = (size_t)(pbase + (t * 16 + lrow) * 4);
        const unsigned short* bp = qkv + p * 768 + h * 32 + lg * 8;
        Qf[t] = *(const bf16x8*)bp;
        Kf[t] = *(const bf16x8*)(bp + 256);
    }

    // ---- V gather (issue early; latency hides under QK^T + softmax) ----
    // lane needs V[k = lg*8+j2][h*32 + d0 + lrow], d0 in {0,16}
    unsigned short v0[8], v1[8];
    #pragma unroll
    for (int j2 = 0; j2 < 8; ++j2) {
        size_t p = (size_t)(pbase + (lg * 8 + j2) * 4);
        const unsigned short* vp = qkv + p * 768 + 512 + h * 32 + lrow;
        v0[j2] = vp[0];
        v1[j2] = vp[16];
    }

    // ---- batch ids (sentinels: pad-q = -1, pad-k = -2, never equal) ----
    int bq[2];
    #pragma unroll
    for (int j = 0; j < 2; ++j) {
        int r = j * 16 + lrow;
        int p = pbase + r * 4;
        bq[j] = (r < KWIN && p < N_TOK) ? batch_idx[p] : -1;
    }
    int bk[2][4];
    #pragma unroll
    for (int i = 0; i < 2; ++i)
        #pragma unroll
        for (int rr = 0; rr < 4; ++rr) {
            int r = i * 16 + lg * 4 + rr;
            int p = pbase + r * 4;
            bk[i][rr] = (r < KWIN && p < N_TOK) ? batch_idx[p] : -2;
        }

    // ---- QK^T swapped: S^T[k][q]; D col = q = lane&15, row = k = lg*4+r ----
    f32x4 accS[2][2];
    #pragma unroll
    for (int i = 0; i < 2; ++i)
        #pragma unroll
        for (int j = 0; j < 2; ++j)
            #pragma unroll
            for (int r = 0; r < 4; ++r) accS[i][j][r] = 0.f;
    #pragma unroll
    for (int i = 0; i < 2; ++i)
        #pragma unroll
        for (int j = 0; j < 2; ++j)
            accS[i][j] = __builtin_amdgcn_mfma_f32_16x16x32_bf16(Kf[i], Qf[j], accS[i][j], 0, 0, 0);

    // ---- masked softmax over k, per q column (q = j*16+lrow) ----
    float sv[2][2][4];
    float mx[2] = { -3.0e38f, -3.0e38f };
    #pragma unroll
    for (int i = 0; i < 2; ++i)
        #pragma unroll
        for (int j = 0; j < 2; ++j)
            #pragma unroll
            for (int rr = 0; rr < 4; ++rr) {
                float val = (bk[i][rr] == bq[j]) ? accS[i][j][rr] * SCALE_F : -1.0e9f;
                sv[i][j][rr] = val;
                mx[j] = fmaxf(mx[j], val);
            }
    mx[0] = fmaxf(mx[0], __shfl_xor(mx[0], 16)); mx[0] = fmaxf(mx[0], __shfl_xor(mx[0], 32));
    mx[1] = fmaxf(mx[1], __shfl_xor(mx[1], 16)); mx[1] = fmaxf(mx[1], __shfl_xor(mx[1], 32));
    float sm[2] = { 0.f, 0.f };
    #pragma unroll
    for (int i = 0; i < 2; ++i)
        #pragma unroll
        for (int j = 0; j < 2; ++j)
            #pragma unroll
            for (int rr = 0; rr < 4; ++rr) {
                float e = __expf(sv[i][j][rr] - mx[j]);
                sv[i][j][rr] = e;
                sm[j] += e;
            }
    sm[0] += __shfl_xor(sm[0], 16); sm[0] += __shfl_xor(sm[0], 32);
    sm[1] += __shfl_xor(sm[1], 16); sm[1] += __shfl_xor(sm[1], 32);
    float inv[2] = { 1.f / sm[0], 1.f / sm[1] };

    // ---- P -> LDS (bf16, row-XOR swizzled), then read A-fragments ----
    char* pb = (char*)sP[ws_];
    const int swz = (lrow & 7) << 4;                // q&7 == lrow&7 for q = j*16+lrow
    #pragma unroll
    for (int j = 0; j < 2; ++j) {
        int q = j * 16 + lrow;
        #pragma unroll
        for (int i = 0; i < 2; ++i) {
            unsigned lo = (unsigned)f2b(sv[i][j][0] * inv[j]) | ((unsigned)f2b(sv[i][j][1] * inv[j]) << 16);
            unsigned hi = (unsigned)f2b(sv[i][j][2] * inv[j]) | ((unsigned)f2b(sv[i][j][3] * inv[j]) << 16);
            *(uint2*)(pb + q * 128 + ((i * 32 + lg * 8) ^ swz)) = make_uint2(lo, hi);
        }
    }
    bf16x8 AP[2];
    #pragma unroll
    for (int jj = 0; jj < 2; ++jj)
        AP[jj] = *(const bf16x8*)(pb + (jj * 16 + lrow) * 128 + ((lg * 16) ^ swz));

    // ---- PV: B fragments from V gather; D row = q = lg*4+r, col = d = lane&15 ----
    union { bf16x8 v; unsigned short s[8]; } B0, B1;
    #pragma unroll
    for (int j2 = 0; j2 < 8; ++j2) { B0.s[j2] = v0[j2]; B1.s[j2] = v1[j2]; }
    f32x4 accO[2][2];
    #pragma unroll
    for (int i = 0; i < 2; ++i)
        #pragma unroll
        for (int j = 0; j < 2; ++j)
            #pragma unroll
            for (int r = 0; r < 4; ++r) accO[i][j][r] = 0.f;
    #pragma unroll
    for (int jj = 0; jj < 2; ++jj) {
        accO[jj][0] = __builtin_amdgcn_mfma_f32_16x16x32_bf16(AP[jj], B0.v, accO[jj][0], 0, 0, 0);
        accO[jj][1] = __builtin_amdgcn_mfma_f32_16x16x32_bf16(AP[jj], B1.v, accO[jj][1], 0, 0, 0);
    }

    // ---- store: q = jj*16 + lg*4 + rr, channel = h*32 + {lrow, 16+lrow} ----
    #pragma unroll
    for (int jj = 0; jj < 2; ++jj)
        #pragma unroll
        for (int rr = 0; rr < 4; ++rr) {
            int q = jj * 16 + lg * 4 + rr;
            int p = pbase + q * 4;
            if (q < KWIN && p < N_TOK) {
                unsigned short* op = attn_out + (size_t)p * CDIM + h * 32;
                op[lrow]      = f2b(accO[jj][0][rr]);
                op[16 + lrow] = f2b(accO[jj][1][rr]);
            }
        }
}

// ---------------- host launch ----------------

extern "C" void kernel_launch(void* const* d_in, const int* in_sizes, int n_in,
                              void* d_out, int out_size, void* d_ws, size_t ws_size,
                              hipStream_t stream) {
    const float* data    = (const float*)d_in[0];
    const float* qkv_w   = (const float*)d_in[1];
    const float* qkv_b   = (const float*)d_in[2];
    const float* proj_w  = (const float*)d_in[3];
    const float* proj_b  = (const float*)d_in[4];
    const int*   batch_i = (const int*)d_in[5];

    char* ws = (char*)d_ws;
    size_t off = 0;
    unsigned short* dataB  = (unsigned short*)(ws + off); off += (size_t)MP * CDIM * 2;
    unsigned short* qkvB   = (unsigned short*)(ws + off); off += (size_t)MP * 768 * 2;
    unsigned short* attnB  = (unsigned short*)(ws + off); off += (size_t)MP * CDIM * 2;
    unsigned short* wqkvB  = (unsigned short*)(ws + off); off += (size_t)768 * 256 * 2;
    unsigned short* wprojB = (unsigned short*)(ws + off); off += (size_t)256 * 256 * 2;
    if (ws_size < off) return;

    cvt_data_kernel<<<MP / 8, 256, 0, stream>>>(data, dataB);
    cvt_w_kernel<<<(768 * 256 / 8 + 255) / 256, 256, 0, stream>>>(qkv_w, wqkvB, 768 * 256 / 8);
    cvt_w_kernel<<<(256 * 256 / 8 + 255) / 256, 256, 0, stream>>>(proj_w, wprojB, 256 * 256 / 8);
    zero_pad_kernel<<<12, 256, 0, stream>>>(attnB);

    gemm_kernel<768, false><<<dim3(6, MP / 128), 256, 0, stream>>>(dataB, wqkvB, qkv_b, qkvB, MP);
    attn_kernel<<<NWIN * HEADS / 4, 256, 0, stream>>>(qkvB, batch_i, attnB);
    gemm_kernel<256, true><<<dim3(2, MP / 128), 256, 0, stream>>>(attnB, wprojB, proj_b, d_out, N_TOK);
}